// Round 11
// baseline (479.512 us; speedup 1.0000x reference)
//
#include <hip/hip_runtime.h>
#include <hip/hip_bf16.h>
#include <stdint.h>

#define T_TOK 32768
#define IN_D  256
#define HID_D 1024
#define OUT_D 256
#define NE    8
#define BM    128
#define HC    32
#define NCH   (HID_D / HC)   // 32

typedef unsigned short u16;
typedef __attribute__((ext_vector_type(8))) __bf16 bf16x8;
typedef __attribute__((ext_vector_type(4))) float f32x4;
typedef __attribute__((ext_vector_type(4))) unsigned int u32x4;
typedef __attribute__((ext_vector_type(2))) unsigned int u32x2;

__device__ __forceinline__ u16 f2bf(float f) {
  unsigned int u = __builtin_bit_cast(unsigned int, f);
  u = (u + 0x7FFFu + ((u >> 16) & 1u)) >> 16;
  return (u16)u;
}

__device__ __forceinline__ void gload_lds16(const u16* g, u16* l) {
  __builtin_amdgcn_global_load_lds(
      (const __attribute__((address_space(1))) unsigned int*)g,
      (__attribute__((address_space(3))) unsigned int*)l, 16, 0, 0);
}

// ---------------- weight packing: fragment-linear, contiguous 1KB frags ----
__global__ __launch_bounds__(64) void pack_w1_kernel(const float* __restrict__ W1,
                                                     u16* __restrict__ w1p) {
  int b = blockIdx.x;              // (e*32 + c)*16 + f
  int f = b & 15, c = (b >> 4) & 31, e = b >> 9;
  int l = threadIdx.x, l15 = l & 15, l4 = l >> 4;
  int h = c * 32 + (f >> 3) * 16 + l15;
  int k0 = (f & 7) * 32 + l4 * 8;
  unsigned int w[4];
#pragma unroll
  for (int p = 0; p < 4; ++p) {
    u16 a = f2bf(W1[((size_t)e * IN_D + k0 + 2 * p) * HID_D + h]);
    u16 bq = f2bf(W1[((size_t)e * IN_D + k0 + 2 * p + 1) * HID_D + h]);
    w[p] = (unsigned int)a | ((unsigned int)bq << 16);
  }
  *reinterpret_cast<u32x4*>(w1p + (size_t)b * 512 + l * 8) = u32x4{w[0], w[1], w[2], w[3]};
}

__global__ __launch_bounds__(64) void pack_w2_kernel(const float* __restrict__ W2,
                                                     u16* __restrict__ w2p) {
  int b = blockIdx.x;              // (e*32 + c)*16 + f
  int f = b & 15, c = (b >> 4) & 31, e = b >> 9;
  int l = threadIdx.x, l15 = l & 15, l4 = l >> 4;
  int o = f * 16 + l15;
  int k0 = c * 32 + l4 * 8;
  unsigned int w[4];
#pragma unroll
  for (int p = 0; p < 4; ++p) {
    u16 a = f2bf(W2[((size_t)e * HID_D + k0 + 2 * p) * OUT_D + o]);
    u16 bq = f2bf(W2[((size_t)e * HID_D + k0 + 2 * p + 1) * OUT_D + o]);
    w[p] = (unsigned int)a | ((unsigned int)bq << 16);
  }
  *reinterpret_cast<u32x4*>(w2p + (size_t)b * 512 + l * 8) = u32x4{w[0], w[1], w[2], w[3]};
}

// ---------------- router (coalesced, LDS-aggregated counts, fused x->bf16) ----
__global__ __launch_bounds__(256) void router_kernel(
    const float* __restrict__ x, const float* __restrict__ Wg,
    u16* __restrict__ xbf, float* __restrict__ probs, int* __restrict__ counts,
    int* __restrict__ list_tok, float* __restrict__ list_w) {
  __shared__ float wg_s[IN_D * NE];
  __shared__ int lcnt[NE];
  __shared__ int gbase[NE];
  int tid = threadIdx.x;
  for (int i = tid; i < IN_D * NE; i += 256) wg_s[i] = Wg[i];
  if (tid < NE) lcnt[tid] = 0;
  __syncthreads();

  int lane = tid & 63;
  int wave = tid >> 6;
  int q = lane & 3;
  int tk = blockIdx.x * 64 + wave * 16 + (lane >> 2);

  float acc[NE];
#pragma unroll
  for (int e = 0; e < NE; ++e) acc[e] = 0.f;
  const float* xrow = x + (size_t)tk * IN_D;
  u16* xbrow = xbf + (size_t)tk * IN_D;
#pragma unroll
  for (int i = 0; i < 16; ++i) {
    int c = i * 4 + q;
    f32x4 v = *reinterpret_cast<const f32x4*>(xrow + c * 4);
    unsigned int lo = (unsigned int)f2bf(v[0]) | ((unsigned int)f2bf(v[1]) << 16);
    unsigned int hi = (unsigned int)f2bf(v[2]) | ((unsigned int)f2bf(v[3]) << 16);
    *reinterpret_cast<u32x2*>(xbrow + c * 4) = u32x2{lo, hi};
#pragma unroll
    for (int j = 0; j < 4; ++j) {
      const float* wr = &wg_s[(c * 4 + j) * NE];
#pragma unroll
      for (int e = 0; e < NE; ++e) acc[e] = fmaf(v[j], wr[e], acc[e]);
    }
  }
#pragma unroll
  for (int e = 0; e < NE; ++e) {
    acc[e] += __shfl_xor(acc[e], 1);
    acc[e] += __shfl_xor(acc[e], 2);
  }
  float m = acc[0];
#pragma unroll
  for (int e = 1; e < NE; ++e) m = fmaxf(m, acc[e]);
  float p[NE], s = 0.f;
#pragma unroll
  for (int e = 0; e < NE; ++e) { p[e] = expf(acc[e] - m); s += p[e]; }
  float inv = 1.f / s;
#pragma unroll
  for (int e = 0; e < NE; ++e) p[e] *= inv;
  int i0 = 0; float p0 = p[0];
#pragma unroll
  for (int e = 1; e < NE; ++e) if (p[e] > p0) { p0 = p[e]; i0 = e; }
  int i1 = -1; float p1 = -1.f;
#pragma unroll
  for (int e = 0; e < NE; ++e) if (e != i0 && p[e] > p1) { p1 = p[e]; i1 = e; }
  float wsum = p0 + p1;

  int lp0 = 0, lp1 = 0;
  if (q == 0) {
    *reinterpret_cast<f32x4*>(probs + (size_t)tk * NE)     = f32x4{p[0], p[1], p[2], p[3]};
    *reinterpret_cast<f32x4*>(probs + (size_t)tk * NE + 4) = f32x4{p[4], p[5], p[6], p[7]};
    lp0 = atomicAdd(&lcnt[i0], 1);
    lp1 = atomicAdd(&lcnt[i1], 1);
  }
  __syncthreads();
  if (tid < NE) gbase[tid] = atomicAdd(&counts[tid], lcnt[tid]);
  __syncthreads();
  if (q == 0) {
    int e0 = gbase[i0] + lp0;
    list_tok[(size_t)i0 * T_TOK + e0] = tk;
    list_w[(size_t)i0 * T_TOK + e0] = p0 / wsum;
    int e1 = gbase[i1] + lp1;
    list_tok[(size_t)i1 * T_TOK + e1] = tk | (1 << 16);
    list_w[(size_t)i1 * T_TOK + e1] = p1 / wsum;
  }
}

// ---------------- fused expert FFN: BM=128, 8 waves, contiguous DMA ----------
// LDS 74 KB -> 2 blocks/CU (16 waves): whole-block stalls (barrier skew, DMA
// drain) now overlap with the co-resident block. Hs single-buffered (barriers
// already order p1-write/p2-read/next-p1-write). b1 staged once in LDS.
__global__ __launch_bounds__(512, 4) void moe_main_kernel(
    const u16* __restrict__ xbf, const u16* __restrict__ w1p,
    const u16* __restrict__ w2p, const float* __restrict__ b1,
    const float* __restrict__ b2, const int* __restrict__ counts,
    const int* __restrict__ list_tok, const float* __restrict__ list_w,
    float* __restrict__ part) {
  int e = blockIdx.x & 7;
  int tile = blockIdx.x >> 3;
  int cnt = counts[e];
  int base = tile * BM;
  if (base >= cnt) return;

  __shared__ __align__(16) u16 W1s[2][16 * 512];  // 32 KB
  __shared__ __align__(16) u16 W2s[2][16 * 512];  // 32 KB
  __shared__ __align__(16) u16 Hs[8 * 512];       //  8 KB (single buffer)
  __shared__ float Bs[HID_D];                     //  4 KB (b1 staged)
  __shared__ int toks[BM];
  __shared__ float gw[BM];

  int tid = threadIdx.x;
  int wave = tid >> 6;            // 0..7
  int lane = tid & 63;
  const int l15 = lane & 15;
  const int l4 = lane >> 4;
  const int hh = wave & 1;        // p1 h-half (16 h of 32)
  const int tt = wave >> 1;       // p1 t-quarter (32 t of 128)

  if (tid < BM) {
    int idx = base + tid;
    int tv = 0; float w = 0.f;
    if (idx < cnt) { tv = list_tok[(size_t)e * T_TOK + idx]; w = list_w[(size_t)e * T_TOK + idx]; }
    toks[tid] = tv;
    gw[tid] = w;
  }
  // stage b1 for this expert (1024 floats, once)
#pragma unroll
  for (int j = 0; j < 2; ++j) Bs[tid + j * 512] = b1[(size_t)e * HID_D + tid + j * 512];

  const u16* w1base = w1p + (size_t)e * NCH * 16 * 512;
  const u16* w2base = w2p + (size_t)e * NCH * 16 * 512;

  // stage chunk c: 32 contiguous 1KB frags, 4 per wave (wave-uniform LDS base)
  auto stage = [&](int c, int buf) {
#pragma unroll
    for (int j2 = 0; j2 < 4; ++j2) {
      int f = wave * 4 + j2;
      if (f < 16)
        gload_lds16(w1base + ((size_t)c * 16 + f) * 512 + lane * 8, &W1s[buf][f * 512]);
      else
        gload_lds16(w2base + ((size_t)c * 16 + (f - 16)) * 512 + lane * 8,
                    &W2s[buf][(f - 16) * 512]);
    }
  };

  stage(0, 0);
  __syncthreads();  // toks/Bs ready + chunk-0 staged (full drain, once)

  // X B-fragments (chunk-invariant), nontemporal to keep weights L2-resident
  const u16* xr0 = xbf + (size_t)(toks[tt * 32 + l15] & 0xFFFF) * IN_D + l4 * 8;
  const u16* xr1 = xbf + (size_t)(toks[tt * 32 + 16 + l15] & 0xFFFF) * IN_D + l4 * 8;
  u32x4 bx[2][8];
#pragma unroll
  for (int kk = 0; kk < 8; ++kk) {
    bx[0][kk] = __builtin_nontemporal_load(reinterpret_cast<const u32x4*>(xr0 + kk * 32));
    bx[1][kk] = __builtin_nontemporal_load(reinterpret_cast<const u32x4*>(xr1 + kk * 32));
  }

  f32x4 acc[2][8];
#pragma unroll
  for (int a = 0; a < 2; ++a)
#pragma unroll
    for (int b = 0; b < 8; ++b) acc[a][b] = f32x4{0.f, 0.f, 0.f, 0.f};

#pragma unroll 1
  for (int c = 0; c < NCH; ++c) {
    int buf = c & 1;
    if (c + 1 < NCH) stage(c + 1, buf ^ 1);   // issue early, zero-VGPR DMA

    // ---- phase 1: H(c) = relu(W1_chunk @ X^T + b1); wave = 16h x 32t ----
    {
      f32x4 accH[2];
      accH[0] = f32x4{0.f, 0.f, 0.f, 0.f};
      accH[1] = f32x4{0.f, 0.f, 0.f, 0.f};
#pragma unroll
      for (int kk = 0; kk < 8; ++kk) {
        const char* pa = reinterpret_cast<const char*>(&W1s[buf][0]) +
                         (hh * 8 + kk) * 1024 + lane * 16;
        bf16x8 a = __builtin_bit_cast(bf16x8, *reinterpret_cast<const u32x4*>(pa));
        accH[0] = __builtin_amdgcn_mfma_f32_16x16x32_bf16(a, __builtin_bit_cast(bf16x8, bx[0][kk]), accH[0], 0, 0, 0);
        accH[1] = __builtin_amdgcn_mfma_f32_16x16x32_bf16(a, __builtin_bit_cast(bf16x8, bx[1][kk]), accH[1], 0, 0, 0);
      }
      f32x4 bias = *reinterpret_cast<const f32x4*>(&Bs[c * HC + hh * 16 + l4 * 4]);
#pragma unroll
      for (int nf = 0; nf < 2; ++nf) {
        u16 q0 = f2bf(fmaxf(accH[nf][0] + bias[0], 0.f));
        u16 q1 = f2bf(fmaxf(accH[nf][1] + bias[1], 0.f));
        u16 q2 = f2bf(fmaxf(accH[nf][2] + bias[2], 0.f));
        u16 q3 = f2bf(fmaxf(accH[nf][3] + bias[3], 0.f));
        unsigned int lo = (unsigned int)q0 | ((unsigned int)q1 << 16);
        unsigned int hi = (unsigned int)q2 | ((unsigned int)q3 << 16);
        int tf = tt * 2 + nf;
        char* p = reinterpret_cast<char*>(&Hs[0]) + tf * 1024 +
                  ((hh * 2 + (l4 >> 1)) * 16 + l15) * 16 + (l4 & 1) * 8;
        *reinterpret_cast<u32x2*>(p) = u32x2{lo, hi};
      }
    }
    asm volatile("s_waitcnt lgkmcnt(0)" ::: "memory");
    __builtin_amdgcn_s_barrier();

    // ---- phase 2: acc += W2_chunk @ H(c); wave = 32o x 128t, K=32 ----
    {
      bf16x8 bh[8];
#pragma unroll
      for (int tf = 0; tf < 8; ++tf)
        bh[tf] = __builtin_bit_cast(bf16x8, *reinterpret_cast<const u32x4*>(
            reinterpret_cast<const char*>(&Hs[0]) + tf * 1024 + lane * 16));
#pragma unroll
      for (int of = 0; of < 2; ++of) {
        const char* pa = reinterpret_cast<const char*>(&W2s[buf][0]) +
                         (wave * 2 + of) * 1024 + lane * 16;
        bf16x8 a = __builtin_bit_cast(bf16x8, *reinterpret_cast<const u32x4*>(pa));
#pragma unroll
        for (int tf = 0; tf < 8; ++tf)
          acc[of][tf] = __builtin_amdgcn_mfma_f32_16x16x32_bf16(a, bh[tf], acc[of][tf], 0, 0, 0);
      }
    }
    // end barrier: next chunk's DMA landed (vmcnt only); also orders Hs reuse
    asm volatile("s_waitcnt vmcnt(0)" ::: "memory");
    __builtin_amdgcn_s_barrier();
  }

  // ---- epilogue: part[slot][tok][o] = w * (acc + b2)  (non-temporal) ----
#pragma unroll
  for (int of = 0; of < 2; ++of) {
    int ob = (wave * 2 + of) * 16 + l4 * 4;
    f32x4 bv = *reinterpret_cast<const f32x4*>(b2 + (size_t)e * OUT_D + ob);
#pragma unroll
    for (int tf = 0; tf < 8; ++tf) {
      int trow = tf * 16 + l15;
      if (base + trow < cnt) {
        int tv = toks[trow];
        int tok = tv & 0xFFFF;
        int slot = tv >> 16;
        float w = gw[trow];
        f32x4 o;
#pragma unroll
        for (int r = 0; r < 4; ++r) o[r] = w * (acc[of][tf][r] + bv[r]);
        __builtin_nontemporal_store(
            o, reinterpret_cast<f32x4*>(part + ((size_t)slot * T_TOK + tok) * OUT_D + ob));
      }
    }
  }
}

// ---------------- combine: out = part0 + part1 ----------------
__global__ __launch_bounds__(256) void combine_kernel(const float* __restrict__ part,
                                                      float* __restrict__ out) {
  size_t i = (size_t)blockIdx.x * 256 + threadIdx.x;
  f32x4 a = __builtin_nontemporal_load(reinterpret_cast<const f32x4*>(part) + i);
  f32x4 b = __builtin_nontemporal_load(
      reinterpret_cast<const f32x4*>(part + (size_t)T_TOK * OUT_D) + i);
  f32x4 o = a + b;
  __builtin_nontemporal_store(o, reinterpret_cast<f32x4*>(out) + i);
}

// ---------------- launch ----------------
extern "C" void kernel_launch(void* const* d_in, const int* in_sizes, int n_in,
                              void* d_out, int out_size, void* d_ws, size_t ws_size,
                              hipStream_t stream) {
  const float* x  = (const float*)d_in[0];
  const float* Wg = (const float*)d_in[1];
  const float* W1 = (const float*)d_in[2];
  const float* b1 = (const float*)d_in[3];
  const float* W2 = (const float*)d_in[4];
  const float* b2 = (const float*)d_in[5];
  float* out = (float*)d_out;

  char* ws = (char*)d_ws;
  constexpr size_t OFF_XBF  = 0;
  constexpr size_t OFF_W1P  = (size_t)T_TOK * IN_D * 2;                   // 16 MB
  constexpr size_t OFF_W2P  = OFF_W1P + (size_t)NE * HID_D * IN_D * 2;    // +4 MB
  constexpr size_t OFF_CNT  = OFF_W2P + (size_t)NE * OUT_D * HID_D * 2;   // +4 MB
  constexpr size_t OFF_LTOK = OFF_CNT + 128;
  constexpr size_t OFF_LW   = OFF_LTOK + (size_t)NE * T_TOK * 4;
  constexpr size_t OFF_PART = OFF_LW + (size_t)NE * T_TOK * 4;

  u16*   xbf      = (u16*)(ws + OFF_XBF);
  u16*   w1p      = (u16*)(ws + OFF_W1P);
  u16*   w2p      = (u16*)(ws + OFF_W2P);
  int*   counts   = (int*)(ws + OFF_CNT);
  int*   list_tok = (int*)(ws + OFF_LTOK);
  float* list_w   = (float*)(ws + OFF_LW);
  float* part     = (float*)(ws + OFF_PART);
  float* probs    = out + (size_t)T_TOK * OUT_D;

  hipMemsetAsync(counts, 0, NE * sizeof(int), stream);

  pack_w1_kernel<<<NE * NCH * 16, 64, 0, stream>>>(W1, w1p);
  pack_w2_kernel<<<NE * NCH * 16, 64, 0, stream>>>(W2, w2p);
  router_kernel<<<T_TOK / 64, 256, 0, stream>>>(x, Wg, xbf, probs, counts,
                                                list_tok, list_w);

  moe_main_kernel<<<(T_TOK / BM) * NE, 512, 0, stream>>>(
      xbf, w1p, w2p, b1, b2, counts, list_tok, list_w, part);

  combine_kernel<<<(T_TOK * OUT_D / 4) / 256, 256, 0, stream>>>(part, out);
}

// Round 12
// 160.077 us; speedup vs baseline: 2.9955x; 2.9955x over previous
//
#include <hip/hip_runtime.h>
#include <hip/hip_bf16.h>
#include <stdint.h>

#define T_TOK 32768
#define IN_D  256
#define HID_D 1024
#define OUT_D 256
#define NE    8
#define BM    64
#define HC    32
#define NCH   (HID_D / HC)   // 32

typedef unsigned short u16;
typedef __attribute__((ext_vector_type(8))) __bf16 bf16x8;
typedef __attribute__((ext_vector_type(4))) float f32x4;
typedef __attribute__((ext_vector_type(4))) unsigned int u32x4;
typedef __attribute__((ext_vector_type(2))) unsigned int u32x2;

__device__ __forceinline__ u16 f2bf(float f) {
  unsigned int u = __builtin_bit_cast(unsigned int, f);
  u = (u + 0x7FFFu + ((u >> 16) & 1u)) >> 16;
  return (u16)u;
}

__device__ __forceinline__ void gload_lds16(const u16* g, u16* l) {
  __builtin_amdgcn_global_load_lds(
      (const __attribute__((address_space(1))) unsigned int*)g,
      (__attribute__((address_space(3))) unsigned int*)l, 16, 0, 0);
}

// ---------------- weight packing: fragment-linear, contiguous 1KB frags ----
__global__ __launch_bounds__(64) void pack_w1_kernel(const float* __restrict__ W1,
                                                     u16* __restrict__ w1p) {
  int b = blockIdx.x;              // (e*32 + c)*16 + f
  int f = b & 15, c = (b >> 4) & 31, e = b >> 9;
  int l = threadIdx.x, l15 = l & 15, l4 = l >> 4;
  int h = c * 32 + (f >> 3) * 16 + l15;
  int k0 = (f & 7) * 32 + l4 * 8;
  unsigned int w[4];
#pragma unroll
  for (int p = 0; p < 4; ++p) {
    u16 a = f2bf(W1[((size_t)e * IN_D + k0 + 2 * p) * HID_D + h]);
    u16 bq = f2bf(W1[((size_t)e * IN_D + k0 + 2 * p + 1) * HID_D + h]);
    w[p] = (unsigned int)a | ((unsigned int)bq << 16);
  }
  *reinterpret_cast<u32x4*>(w1p + (size_t)b * 512 + l * 8) = u32x4{w[0], w[1], w[2], w[3]};
}

__global__ __launch_bounds__(64) void pack_w2_kernel(const float* __restrict__ W2,
                                                     u16* __restrict__ w2p) {
  int b = blockIdx.x;              // (e*32 + c)*16 + f
  int f = b & 15, c = (b >> 4) & 31, e = b >> 9;
  int l = threadIdx.x, l15 = l & 15, l4 = l >> 4;
  int o = f * 16 + l15;
  int k0 = c * 32 + l4 * 8;
  unsigned int w[4];
#pragma unroll
  for (int p = 0; p < 4; ++p) {
    u16 a = f2bf(W2[((size_t)e * HID_D + k0 + 2 * p) * OUT_D + o]);
    u16 bq = f2bf(W2[((size_t)e * HID_D + k0 + 2 * p + 1) * OUT_D + o]);
    w[p] = (unsigned int)a | ((unsigned int)bq << 16);
  }
  *reinterpret_cast<u32x4*>(w2p + (size_t)b * 512 + l * 8) = u32x4{w[0], w[1], w[2], w[3]};
}

// ---------------- router (coalesced, LDS-aggregated counts, fused x->bf16) ----
__global__ __launch_bounds__(256) void router_kernel(
    const float* __restrict__ x, const float* __restrict__ Wg,
    u16* __restrict__ xbf, float* __restrict__ probs, int* __restrict__ counts,
    int* __restrict__ list_tok, float* __restrict__ list_w) {
  __shared__ float wg_s[IN_D * NE];
  __shared__ int lcnt[NE];
  __shared__ int gbase[NE];
  int tid = threadIdx.x;
  for (int i = tid; i < IN_D * NE; i += 256) wg_s[i] = Wg[i];
  if (tid < NE) lcnt[tid] = 0;
  __syncthreads();

  int lane = tid & 63;
  int wave = tid >> 6;
  int q = lane & 3;
  int tk = blockIdx.x * 64 + wave * 16 + (lane >> 2);

  float acc[NE];
#pragma unroll
  for (int e = 0; e < NE; ++e) acc[e] = 0.f;
  const float* xrow = x + (size_t)tk * IN_D;
  u16* xbrow = xbf + (size_t)tk * IN_D;
#pragma unroll
  for (int i = 0; i < 16; ++i) {
    int c = i * 4 + q;
    f32x4 v = *reinterpret_cast<const f32x4*>(xrow + c * 4);
    unsigned int lo = (unsigned int)f2bf(v[0]) | ((unsigned int)f2bf(v[1]) << 16);
    unsigned int hi = (unsigned int)f2bf(v[2]) | ((unsigned int)f2bf(v[3]) << 16);
    *reinterpret_cast<u32x2*>(xbrow + c * 4) = u32x2{lo, hi};
#pragma unroll
    for (int j = 0; j < 4; ++j) {
      const float* wr = &wg_s[(c * 4 + j) * NE];
#pragma unroll
      for (int e = 0; e < NE; ++e) acc[e] = fmaf(v[j], wr[e], acc[e]);
    }
  }
#pragma unroll
  for (int e = 0; e < NE; ++e) {
    acc[e] += __shfl_xor(acc[e], 1);
    acc[e] += __shfl_xor(acc[e], 2);
  }
  float m = acc[0];
#pragma unroll
  for (int e = 1; e < NE; ++e) m = fmaxf(m, acc[e]);
  float p[NE], s = 0.f;
#pragma unroll
  for (int e = 0; e < NE; ++e) { p[e] = expf(acc[e] - m); s += p[e]; }
  float inv = 1.f / s;
#pragma unroll
  for (int e = 0; e < NE; ++e) p[e] *= inv;
  int i0 = 0; float p0 = p[0];
#pragma unroll
  for (int e = 1; e < NE; ++e) if (p[e] > p0) { p0 = p[e]; i0 = e; }
  int i1 = -1; float p1 = -1.f;
#pragma unroll
  for (int e = 0; e < NE; ++e) if (e != i0 && p[e] > p1) { p1 = p[e]; i1 = e; }
  float wsum = p0 + p1;

  int lp0 = 0, lp1 = 0;
  if (q == 0) {
    *reinterpret_cast<f32x4*>(probs + (size_t)tk * NE)     = f32x4{p[0], p[1], p[2], p[3]};
    *reinterpret_cast<f32x4*>(probs + (size_t)tk * NE + 4) = f32x4{p[4], p[5], p[6], p[7]};
    lp0 = atomicAdd(&lcnt[i0], 1);
    lp1 = atomicAdd(&lcnt[i1], 1);
  }
  __syncthreads();
  if (tid < NE) gbase[tid] = atomicAdd(&counts[tid], lcnt[tid]);
  __syncthreads();
  if (q == 0) {
    int e0 = gbase[i0] + lp0;
    list_tok[(size_t)i0 * T_TOK + e0] = tk;
    list_w[(size_t)i0 * T_TOK + e0] = p0 / wsum;
    int e1 = gbase[i1] + lp1;
    list_tok[(size_t)i1 * T_TOK + e1] = tk | (1 << 16);
    list_w[(size_t)i1 * T_TOK + e1] = p1 / wsum;
  }
}

// ---------------- fused expert FFN: BM=64, 8 waves, 2 blocks/CU ----------
// Register budget (the r11 lesson): acc[2][4]=32 (AGPR) + bx[8]=32 (VGPR)
// + working ~40 => ~110 unified <= 128 cap of (512,4). LDS 72.6 KB -> two
// blocks co-resident (4 waves/SIMD) so barrier drains overlap across blocks.
// p1: wave = 16h x 16t (hh=wave&1, tt=wave>>1); p2: wave = 32o x 64t.
__global__ __launch_bounds__(512, 4) void moe_main_kernel(
    const u16* __restrict__ xbf, const u16* __restrict__ w1p,
    const u16* __restrict__ w2p, const float* __restrict__ b1,
    const float* __restrict__ b2, const int* __restrict__ counts,
    const int* __restrict__ list_tok, const float* __restrict__ list_w,
    float* __restrict__ part) {
  int e = blockIdx.x & 7;
  int tile = blockIdx.x >> 3;
  int cnt = counts[e];
  int base = tile * BM;
  if (base >= cnt) return;

  __shared__ __align__(16) u16 W1s[2][16 * 512];  // 32 KB
  __shared__ __align__(16) u16 W2s[2][16 * 512];  // 32 KB
  __shared__ __align__(16) u16 Hs[4 * 512];       //  4 KB (single buffer)
  __shared__ float Bs[HID_D];                     //  4 KB (b1 staged)
  __shared__ int toks[BM];
  __shared__ float gw[BM];

  int tid = threadIdx.x;
  int wave = tid >> 6;            // 0..7
  int lane = tid & 63;
  const int l15 = lane & 15;
  const int l4 = lane >> 4;
  const int hh = wave & 1;        // p1 h-half (16 h of 32)
  const int tt = wave >> 1;       // p1 t-quarter (16 t of 64)

  if (tid < BM) {
    int idx = base + tid;
    int tv = 0; float w = 0.f;
    if (idx < cnt) { tv = list_tok[(size_t)e * T_TOK + idx]; w = list_w[(size_t)e * T_TOK + idx]; }
    toks[tid] = tv;
    gw[tid] = w;
  }
  // stage b1 for this expert (1024 floats, once)
#pragma unroll
  for (int j = 0; j < 2; ++j) Bs[tid + j * 512] = b1[(size_t)e * HID_D + tid + j * 512];

  const u16* w1base = w1p + (size_t)e * NCH * 16 * 512;
  const u16* w2base = w2p + (size_t)e * NCH * 16 * 512;

  // stage chunk c: 32 contiguous 1KB frags, 4 per wave (wave-uniform LDS base)
  auto stage = [&](int c, int buf) {
#pragma unroll
    for (int j2 = 0; j2 < 4; ++j2) {
      int f = wave * 4 + j2;
      if (f < 16)
        gload_lds16(w1base + ((size_t)c * 16 + f) * 512 + lane * 8, &W1s[buf][f * 512]);
      else
        gload_lds16(w2base + ((size_t)c * 16 + (f - 16)) * 512 + lane * 8,
                    &W2s[buf][(f - 16) * 512]);
    }
  };

  stage(0, 0);
  __syncthreads();  // toks/Bs ready + chunk-0 staged (full drain, once)

  // X B-fragments (chunk-invariant): wave owns 16 tokens -> bx[8] = 32 VGPRs
  u32x4 bx[8];
  {
    const u16* xr = xbf + (size_t)(toks[tt * 16 + l15] & 0xFFFF) * IN_D + l4 * 8;
#pragma unroll
    for (int kk = 0; kk < 8; ++kk)
      bx[kk] = __builtin_nontemporal_load(reinterpret_cast<const u32x4*>(xr + kk * 32));
  }

  f32x4 acc[2][4];
#pragma unroll
  for (int a = 0; a < 2; ++a)
#pragma unroll
    for (int b = 0; b < 4; ++b) acc[a][b] = f32x4{0.f, 0.f, 0.f, 0.f};

#pragma unroll 1
  for (int c = 0; c < NCH; ++c) {
    int buf = c & 1;
    if (c + 1 < NCH) stage(c + 1, buf ^ 1);   // issue early, zero-VGPR DMA

    // ---- phase 1: H(c) = relu(W1_chunk @ X^T + b1); wave = 16h x 16t ----
    {
      f32x4 accH = f32x4{0.f, 0.f, 0.f, 0.f};
#pragma unroll
      for (int kk = 0; kk < 8; ++kk) {
        const char* pa = reinterpret_cast<const char*>(&W1s[buf][0]) +
                         (hh * 8 + kk) * 1024 + lane * 16;
        bf16x8 a = __builtin_bit_cast(bf16x8, *reinterpret_cast<const u32x4*>(pa));
        accH = __builtin_amdgcn_mfma_f32_16x16x32_bf16(a, __builtin_bit_cast(bf16x8, bx[kk]), accH, 0, 0, 0);
      }
      f32x4 bias = *reinterpret_cast<const f32x4*>(&Bs[c * HC + hh * 16 + l4 * 4]);
      u16 q0 = f2bf(fmaxf(accH[0] + bias[0], 0.f));
      u16 q1 = f2bf(fmaxf(accH[1] + bias[1], 0.f));
      u16 q2 = f2bf(fmaxf(accH[2] + bias[2], 0.f));
      u16 q3 = f2bf(fmaxf(accH[3] + bias[3], 0.f));
      unsigned int lo = (unsigned int)q0 | ((unsigned int)q1 << 16);
      unsigned int hi = (unsigned int)q2 | ((unsigned int)q3 << 16);
      // H frag tt: B-frag layout (t=l15, h-piece=l4'); h = hh*16 + l4*4 + i
      char* p = reinterpret_cast<char*>(&Hs[0]) + tt * 1024 +
                ((hh * 2 + (l4 >> 1)) * 16 + l15) * 16 + (l4 & 1) * 8;
      *reinterpret_cast<u32x2*>(p) = u32x2{lo, hi};
    }
    asm volatile("s_waitcnt lgkmcnt(0)" ::: "memory");
    __builtin_amdgcn_s_barrier();

    // ---- phase 2: acc += W2_chunk @ H(c); wave = 32o x 64t, K=32 ----
    {
#pragma unroll
      for (int of = 0; of < 2; ++of) {
        const char* pa = reinterpret_cast<const char*>(&W2s[buf][0]) +
                         (wave * 2 + of) * 1024 + lane * 16;
        bf16x8 a = __builtin_bit_cast(bf16x8, *reinterpret_cast<const u32x4*>(pa));
#pragma unroll
        for (int tf = 0; tf < 4; ++tf) {
          bf16x8 bh = __builtin_bit_cast(bf16x8, *reinterpret_cast<const u32x4*>(
              reinterpret_cast<const char*>(&Hs[0]) + tf * 1024 + lane * 16));
          acc[of][tf] = __builtin_amdgcn_mfma_f32_16x16x32_bf16(a, bh, acc[of][tf], 0, 0, 0);
        }
      }
    }
    // end barrier: next chunk's DMA landed (vmcnt only); also orders Hs reuse
    asm volatile("s_waitcnt vmcnt(0)" ::: "memory");
    __builtin_amdgcn_s_barrier();
  }

  // ---- epilogue: part[slot][tok][o] = w * (acc + b2)  (non-temporal) ----
#pragma unroll
  for (int of = 0; of < 2; ++of) {
    int ob = (wave * 2 + of) * 16 + l4 * 4;
    f32x4 bv = *reinterpret_cast<const f32x4*>(b2 + (size_t)e * OUT_D + ob);
#pragma unroll
    for (int tf = 0; tf < 4; ++tf) {
      int trow = tf * 16 + l15;
      if (base + trow < cnt) {
        int tv = toks[trow];
        int tok = tv & 0xFFFF;
        int slot = tv >> 16;
        float w = gw[trow];
        f32x4 o;
#pragma unroll
        for (int r = 0; r < 4; ++r) o[r] = w * (acc[of][tf][r] + bv[r]);
        __builtin_nontemporal_store(
            o, reinterpret_cast<f32x4*>(part + ((size_t)slot * T_TOK + tok) * OUT_D + ob));
      }
    }
  }
}

// ---------------- combine: out = part0 + part1 ----------------
__global__ __launch_bounds__(256) void combine_kernel(const float* __restrict__ part,
                                                      float* __restrict__ out) {
  size_t i = (size_t)blockIdx.x * 256 + threadIdx.x;
  f32x4 a = __builtin_nontemporal_load(reinterpret_cast<const f32x4*>(part) + i);
  f32x4 b = __builtin_nontemporal_load(
      reinterpret_cast<const f32x4*>(part + (size_t)T_TOK * OUT_D) + i);
  f32x4 o = a + b;
  __builtin_nontemporal_store(o, reinterpret_cast<f32x4*>(out) + i);
}

// ---------------- launch ----------------
extern "C" void kernel_launch(void* const* d_in, const int* in_sizes, int n_in,
                              void* d_out, int out_size, void* d_ws, size_t ws_size,
                              hipStream_t stream) {
  const float* x  = (const float*)d_in[0];
  const float* Wg = (const float*)d_in[1];
  const float* W1 = (const float*)d_in[2];
  const float* b1 = (const float*)d_in[3];
  const float* W2 = (const float*)d_in[4];
  const float* b2 = (const float*)d_in[5];
  float* out = (float*)d_out;

  char* ws = (char*)d_ws;
  constexpr size_t OFF_XBF  = 0;
  constexpr size_t OFF_W1P  = (size_t)T_TOK * IN_D * 2;                   // 16 MB
  constexpr size_t OFF_W2P  = OFF_W1P + (size_t)NE * HID_D * IN_D * 2;    // +4 MB
  constexpr size_t OFF_CNT  = OFF_W2P + (size_t)NE * OUT_D * HID_D * 2;   // +4 MB
  constexpr size_t OFF_LTOK = OFF_CNT + 128;
  constexpr size_t OFF_LW   = OFF_LTOK + (size_t)NE * T_TOK * 4;
  constexpr size_t OFF_PART = OFF_LW + (size_t)NE * T_TOK * 4;

  u16*   xbf      = (u16*)(ws + OFF_XBF);
  u16*   w1p      = (u16*)(ws + OFF_W1P);
  u16*   w2p      = (u16*)(ws + OFF_W2P);
  int*   counts   = (int*)(ws + OFF_CNT);
  int*   list_tok = (int*)(ws + OFF_LTOK);
  float* list_w   = (float*)(ws + OFF_LW);
  float* part     = (float*)(ws + OFF_PART);
  float* probs    = out + (size_t)T_TOK * OUT_D;

  hipMemsetAsync(counts, 0, NE * sizeof(int), stream);

  pack_w1_kernel<<<NE * NCH * 16, 64, 0, stream>>>(W1, w1p);
  pack_w2_kernel<<<NE * NCH * 16, 64, 0, stream>>>(W2, w2p);
  router_kernel<<<T_TOK / 64, 256, 0, stream>>>(x, Wg, xbf, probs, counts,
                                                list_tok, list_w);

  moe_main_kernel<<<(T_TOK / BM) * NE, 512, 0, stream>>>(
      xbf, w1p, w2p, b1, b2, counts, list_tok, list_w, part);

  combine_kernel<<<(T_TOK * OUT_D / 4) / 256, 256, 0, stream>>>(part, out);
}